// Round 10
// baseline (314.130 us; speedup 1.0000x reference)
//
#include <hip/hip_runtime.h>

// EdgeFeature kNN (DGCNN): B=4, D=64, N=4096, K=16, fp32 in/out.
// Ranking replicates the numpy fp32 reference pipeline bit-exactly:
//   sq_n  = numpy pairwise_sum (8-accumulator unroll) of fl(x_d^2)
//   dot   = sequential over d of  a = fmaf(x_d, y_d, a)   (einsum axpy w/ FMA)
//   d2    = fl(fl(sq_n + sq_m) - fl(2*dot));  dist = fl(sqrt(max(d2,0)))
//   order = (dist_f32, index) lexicographic (stable top_k tie-break)
// Key pack: (dist_bits << 32) | m. All packed keys are POSITIVE FINITE f64
// bit patterns (numeric order == bit order), so v_min/max_f64 is an exact
// 2-instr u64 compare-exchange. Sentinel = DBL_MAX bits.
//
// R17 (from R16: partial VALU-saturated at 183us -- untouched. Tail ~131us
//      invariant across 4 edge designs -> consolidate the small stuff):
//   * sq fused into transpose (threads 0..63 compute sq from smT columns,
//     exact numpy pairwise order). One fewer launch, one fewer pc pass.
//   * edge v4: thread = (b,n,k,dhalf). Half-rows hoisted fully into
//     registers (16 float4 back-to-back -> MSHR-coalesced, amp-1), then
//     64 coalesced scalar stores (wave = 4n x 16k = 256B/instr).
//     524288 threads, VGPR ~90 -> ~20 waves/CU: TLP AND amp-1 together.
//   * partial: R10-exact (best measured, reproducible 183-185us).

#define BATCH 4
#define DIMS 64
#define NPTS 4096
#define KNN 16
#define NCHUNK 32
#define CHLEN 128      // NPTS / NCHUNK
#define GSZ 8          // candidates per group: 8 independent FMA chains
#define RN (BATCH * NPTS)
#define MLANES 8       // merge lanes per row
#define MCH (NCHUNK / MLANES)

typedef unsigned long long u64;
typedef unsigned int u32;

__device__ __forceinline__ double sentinel() {
    return __longlong_as_double(0x7FEFFFFFFFFFFFFFLL);   // DBL_MAX bits
}

// ---- kernel 0 (fallback only): per-point squared norm -------------------
__global__ __launch_bounds__(256) void ef_sq_kernel(const float* __restrict__ pc,
                                                    float* __restrict__ sq) {
    int gid = blockIdx.x * 256 + threadIdx.x;     // b*NPTS + n
    int b = gid >> 12;
    int n = gid & (NPTS - 1);
    const float* p = pc + (size_t)b * DIMS * NPTS + n;
    float r[8];
#pragma unroll
    for (int j = 0; j < 8; ++j) {
        float v = p[(size_t)j * NPTS];
        r[j] = __fmul_rn(v, v);
    }
#pragma unroll
    for (int i = 8; i < DIMS; i += 8) {
#pragma unroll
        for (int j = 0; j < 8; ++j) {
            float v = p[(size_t)(i + j) * NPTS];
            r[j] = __fadd_rn(r[j], __fmul_rn(v, v));
        }
    }
    float t01 = __fadd_rn(r[0], r[1]);
    float t23 = __fadd_rn(r[2], r[3]);
    float t45 = __fadd_rn(r[4], r[5]);
    float t67 = __fadd_rn(r[6], r[7]);
    sq[gid] = __fadd_rn(__fadd_rn(t01, t23), __fadd_rn(t45, t67));
}

// ---- kernel 0b: transpose pc[b][d][m] -> pcT[(b*N+m)*64+d]  ++  sq ------
// Threads 0..63 compute sq[m0+m] from smT columns with the EXACT numpy
// pairwise 8-accumulator pattern (same values, same op order as ef_sq).
__global__ __launch_bounds__(256) void ef_transpose(const float* __restrict__ pc,
                                                    float* __restrict__ pcT,
                                                    float* __restrict__ sq) {
    __shared__ float smT[DIMS][65];               // 65: conflict-free both phases
    int tid = threadIdx.x;
    int m0 = blockIdx.x * 64;
    int b = blockIdx.y;
    const float* pcb = pc + (size_t)b * DIMS * NPTS;
#pragma unroll
    for (int i = 0; i < 16; ++i) {                // load: coalesced over m
        int idx = i * 256 + tid;
        int d = idx >> 6;
        int m = idx & 63;
        smT[d][m] = pcb[(size_t)d * NPTS + m0 + m];
    }
    __syncthreads();
    if (tid < 64) {                               // sq: numpy pairwise order
        int m = tid;
        float r[8];
#pragma unroll
        for (int j = 0; j < 8; ++j) {
            float v = smT[j][m];
            r[j] = __fmul_rn(v, v);
        }
#pragma unroll
        for (int i = 8; i < DIMS; i += 8) {
#pragma unroll
            for (int j = 0; j < 8; ++j) {
                float v = smT[i + j][m];
                r[j] = __fadd_rn(r[j], __fmul_rn(v, v));
            }
        }
        float t01 = __fadd_rn(r[0], r[1]);
        float t23 = __fadd_rn(r[2], r[3]);
        float t45 = __fadd_rn(r[4], r[5]);
        float t67 = __fadd_rn(r[6], r[7]);
        sq[b * NPTS + m0 + m] =
            __fadd_rn(__fadd_rn(t01, t23), __fadd_rn(t45, t67));
    }
#pragma unroll
    for (int i = 0; i < 16; ++i) {                // store: coalesced over d
        int idx = i * 256 + tid;
        int m = idx >> 6;
        int d = idx & 63;
        pcT[((size_t)b * NPTS + m0 + m) * DIMS + d] = smT[d][m];
    }
}

// ---- kernel 1: per-(row, chunk) partial top-16, LDS-staged candidates ---
// R10-exact configuration (best measured: 183-185 us, VALU-saturated).
__global__ __launch_bounds__(256, 3) void ef_knn_partial(const float* __restrict__ pc,
                                                         const float* __restrict__ sq,
                                                         u64* __restrict__ pKey) {
    __shared__ float tile[DIMS][CHLEN];           // 32 KB candidate tile
    __shared__ float tileSq[CHLEN];
    int tid = threadIdx.x;
    int r = blockIdx.x * 256 + tid;               // global row: b*NPTS + n
    int c = blockIdx.y;
    int b = (blockIdx.x * 256) >> 12;             // uniform per block
    int n = r & (NPTS - 1);
    int m0 = c * CHLEN;
    const float* pcb = pc + (size_t)b * DIMS * NPTS;

    // per-lane query row: lane n reads pc[b][d][n] -> coalesced across lanes
    float xr[DIMS];
#pragma unroll
    for (int d = 0; d < DIMS; ++d) xr[d] = pcb[(size_t)d * NPTS + n];
    // pin: anchor xr (R9: compiler re-loaded xr per group without this)
#pragma unroll
    for (int d = 0; d < DIMS; ++d) asm volatile("" : "+v"(xr[d]));
    float sqn = sq[r];

    // stage candidate tile [64][128] + its sq row (coalesced float4)
#pragma unroll
    for (int i = 0; i < 8; ++i) {
        int idx = tid + i * 256;                  // float4 slot, 2048 total
        int d = idx >> 5;                         // 32 float4 per row
        int mq = idx & 31;
        float4 v = *(const float4*)(pcb + (size_t)d * NPTS + m0 + mq * 4);
        *(float4*)&tile[d][mq * 4] = v;
    }
    if (tid < CHLEN / 4)
        *(float4*)&tileSq[tid * 4] =
            *(const float4*)(sq + (size_t)b * NPTS + m0 + tid * 4);
    __syncthreads();

    double key[KNN];
#pragma unroll
    for (int j = 0; j < KNN; ++j) key[j] = sentinel();

#define CE(arr, i, jj) { double lo_ = fmin(arr[i], arr[jj]); double hi_ = fmax(arr[i], arr[jj]); arr[i] = lo_; arr[jj] = hi_; }

    for (int g = 0; g < CHLEN; g += GSZ) {
        float acc[GSZ];
#pragma unroll
        for (int j = 0; j < GSZ; ++j) acc[j] = 0.f;
        // d-major: two uniform ds_read_b128 per d-step (broadcast) feed 8
        // independent FMA chains; per-candidate d-order sequential (exact).
#pragma unroll
        for (int d = 0; d < DIMS; ++d) {
            float xv = xr[d];
            float4 lo = *(const float4*)&tile[d][g];
            float4 hi = *(const float4*)&tile[d][g + 4];
            acc[0] = fmaf(xv, lo.x, acc[0]);
            acc[1] = fmaf(xv, lo.y, acc[1]);
            acc[2] = fmaf(xv, lo.z, acc[2]);
            acc[3] = fmaf(xv, lo.w, acc[3]);
            acc[4] = fmaf(xv, hi.x, acc[4]);
            acc[5] = fmaf(xv, hi.y, acc[5]);
            acc[6] = fmaf(xv, hi.z, acc[6]);
            acc[7] = fmaf(xv, hi.w, acc[7]);
        }
        float4 sq_lo = *(const float4*)&tileSq[g];
        float4 sq_hi = *(const float4*)&tileSq[g + 4];
        float sqv[GSZ] = {sq_lo.x, sq_lo.y, sq_lo.z, sq_lo.w,
                          sq_hi.x, sq_hi.y, sq_hi.z, sq_hi.w};
        double s[GSZ];
#pragma unroll
        for (int j = 0; j < GSZ; ++j) {
            int m = m0 + g + j;
            float t1 = __fadd_rn(sqn, sqv[j]);
            float d2 = __fsub_rn(t1, __fmul_rn(2.0f, acc[j]));
            float dist = __fsqrt_rn(fmaxf(d2, 0.f));
            u64 cu = ((u64)__float_as_uint(dist) << 32) | (u64)(u32)m;
            double cand = __longlong_as_double((long long)cu);
            s[j] = (m == n) ? sentinel() : cand;   // self -> +max sentinel
        }
        // sort8: Batcher odd-even mergesort, 19 CE (exact u64 order via f64)
        CE(s, 0, 1) CE(s, 2, 3) CE(s, 4, 5) CE(s, 6, 7)
        CE(s, 0, 2) CE(s, 1, 3) CE(s, 4, 6) CE(s, 5, 7)
        CE(s, 1, 2) CE(s, 5, 6)
        CE(s, 0, 4) CE(s, 1, 5) CE(s, 2, 6) CE(s, 3, 7)
        CE(s, 2, 4) CE(s, 3, 5)
        CE(s, 1, 2) CE(s, 3, 4) CE(s, 5, 6)
        // bitonic half-clean: merge sorted-8 into sorted key[16]
#pragma unroll
        for (int j = 8; j < 16; ++j) key[j] = fmin(key[j], s[15 - j]);
        // bitonic clean of 16: stages 8,4,2,1
#pragma unroll
        for (int st = 8; st >= 1; st >>= 1) {
#pragma unroll
            for (int j = 0; j < KNN; ++j) {
                if ((j & st) == 0) {
                    double a = key[j], d = key[j | st];
                    key[j] = fmin(a, d);
                    key[j | st] = fmax(a, d);
                }
            }
        }
    }
#undef CE

    // layout [c][r][j]: lane writes 128 B contiguous, wave covers 8 KB
    u64* dst = pKey + ((size_t)c * RN + r) * KNN;
#pragma unroll
    for (int j = 0; j < KNN; ++j) dst[j] = (u64)__double_as_longlong(key[j]);
}

// ---- kernel 2: merge 32 sorted partial lists per row, 8 lanes per row ---
__global__ __launch_bounds__(256) void ef_knn_merge(const u64* __restrict__ pKey,
                                                    float* __restrict__ outIdxF) {
    int t = blockIdx.x * 256 + threadIdx.x;       // rows * MLANES = 131072
    int r = t >> 3;
    int s = t & 7;
    double key[KNN];
    {
        const u64* src = pKey + ((size_t)(s * MCH) * RN + r) * KNN;
#pragma unroll
        for (int j = 0; j < KNN; ++j)
            key[j] = __longlong_as_double((long long)src[j]);
    }
    for (int ci = 1; ci < MCH; ++ci) {
        const u64* src = pKey + ((size_t)(s * MCH + ci) * RN + r) * KNN;
        double v[KNN];
#pragma unroll
        for (int j = 0; j < KNN; ++j)
            v[j] = __longlong_as_double((long long)src[j]);
#pragma unroll
        for (int j = 0; j < KNN; ++j) key[j] = fmin(key[j], v[KNN - 1 - j]);
#pragma unroll
        for (int st = 8; st >= 1; st >>= 1) {
#pragma unroll
            for (int j = 0; j < KNN; ++j) {
                if ((j & st) == 0) {
                    double a = key[j], d = key[j | st];
                    key[j] = fmin(a, d);
                    key[j | st] = fmax(a, d);
                }
            }
        }
    }
#pragma unroll
    for (int mask = 1; mask <= 4; mask <<= 1) {
        double oth[KNN];
#pragma unroll
        for (int j = 0; j < KNN; ++j) oth[j] = __shfl_xor(key[j], mask, 64);
#pragma unroll
        for (int j = 0; j < KNN; ++j) key[j] = fmin(key[j], oth[KNN - 1 - j]);
#pragma unroll
        for (int st = 8; st >= 1; st >>= 1) {
#pragma unroll
            for (int j = 0; j < KNN; ++j) {
                if ((j & st) == 0) {
                    double a = key[j], d = key[j | st];
                    key[j] = fmin(a, d);
                    key[j | st] = fmax(a, d);
                }
            }
        }
    }
    if (s == 0) {
        float* dstf = outIdxF + (size_t)r * KNN;
#pragma unroll
        for (int j = 0; j < KNN; ++j)
            dstf[j] = (float)(u32)((u64)__double_as_longlong(key[j]) & 0xFFFFFFFFu);
    }
}

// ---- kernel 3: edge features v4 -----------------------------------------
// Thread = (b,n,k,dhalf): half-rows hoisted fully into registers (loads
// issued back-to-back -> MSHR-coalesced, amp-1), then 64 coalesced scalar
// stores (wave = 4n x 16k -> 256 B per store instr). 524288 threads.
__global__ __launch_bounds__(256) void ef_edge_kernelT(const float* __restrict__ pcT,
                                                       const float* __restrict__ idxF,
                                                       float* __restrict__ out) {
    int t = blockIdx.x * 256 + threadIdx.x;        // 524288
    int k = t & 15;
    int n = (t >> 4) & (NPTS - 1);
    int dh = (t >> 16) & 1;
    int b = t >> 17;
    int m = (int)idxF[(((size_t)b << 12) + n) * KNN + k];
    const float* crow = pcT + (((size_t)b << 12) + n) * DIMS + dh * 32;
    const float* nrow = pcT + (((size_t)b << 12) + m) * DIMS + dh * 32;
    float4 c[8], a[8];
#pragma unroll
    for (int q = 0; q < 8; ++q) c[q] = ((const float4*)crow)[q];
#pragma unroll
    for (int q = 0; q < 8; ++q) a[q] = ((const float4*)nrow)[q];
    float* ob = out + ((size_t)b * 2 * DIMS + dh * 32) * (NPTS * KNN)
                    + (size_t)n * KNN + k;
#pragma unroll
    for (int q = 0; q < 8; ++q) {
        ob[(size_t)(4 * q + 0) * (NPTS * KNN)] = c[q].x;
        ob[(size_t)(4 * q + 1) * (NPTS * KNN)] = c[q].y;
        ob[(size_t)(4 * q + 2) * (NPTS * KNN)] = c[q].z;
        ob[(size_t)(4 * q + 3) * (NPTS * KNN)] = c[q].w;
        ob[(size_t)(DIMS + 4 * q + 0) * (NPTS * KNN)] = a[q].x - c[q].x;
        ob[(size_t)(DIMS + 4 * q + 1) * (NPTS * KNN)] = a[q].y - c[q].y;
        ob[(size_t)(DIMS + 4 * q + 2) * (NPTS * KNN)] = a[q].z - c[q].z;
        ob[(size_t)(DIMS + 4 * q + 3) * (NPTS * KNN)] = a[q].w - c[q].w;
    }
}

// ---- kernel 3 fallback: edge features straight from pc ------------------
__global__ __launch_bounds__(256) void ef_edge_kernel(const float* __restrict__ pc,
                                                      const float* __restrict__ idxF,
                                                      float* __restrict__ out) {
    int gid = blockIdx.x * 256 + threadIdx.x;      // B*N*K = 262144
    int b = gid >> 16;                             // N*K = 65536
    int nk = gid & 65535;
    int n = nk >> 4;
    int m = (int)idxF[gid];
    const float* pcb = pc + (size_t)b * DIMS * NPTS;
    float* ob = out + (size_t)b * 2 * DIMS * NPTS * KNN;
#pragma unroll
    for (int d = 0; d < DIMS; ++d) {
        float cv = pcb[(size_t)d * NPTS + n];
        float nv = pcb[(size_t)d * NPTS + m];
        ob[(size_t)d * (NPTS * KNN) + nk] = cv;
        ob[(size_t)(DIMS + d) * (NPTS * KNN) + nk] = nv - cv;
    }
}

extern "C" void kernel_launch(void* const* d_in, const int* in_sizes, int n_in,
                              void* d_out, int out_size, void* d_ws, size_t ws_size,
                              hipStream_t stream) {
    const float* pc = (const float*)d_in[0];
    float* out = (float*)d_out;

    // Scratch inside the edge-feature region of d_out (fully overwritten by
    // the edge kernel): pKey 67.1 MB ++ sq 64 KB  (< 134 MB). pcT must NOT
    // live in d_out (edge reads it while writing d_out) -> d_ws.
    u64* pKey = (u64*)d_out;                          // [NCHUNK][B*N][KNN] u64
    float* sq = out + 16777216;                       // byte 67,108,864
    float* outIdxF = out + (size_t)BATCH * 2 * DIMS * NPTS * KNN; // final idx
    float* pcT = (float*)d_ws;                        // 16 MB
    bool useT = ws_size >= (size_t)BATCH * NPTS * DIMS * sizeof(float);

    if (useT) {
        ef_transpose<<<dim3(NPTS / 64, BATCH), 256, 0, stream>>>(pc, pcT, sq);
    } else {
        ef_sq_kernel<<<(BATCH * NPTS) / 256, 256, 0, stream>>>(pc, sq);
    }
    ef_knn_partial<<<dim3(RN / 256, NCHUNK), 256, 0, stream>>>(pc, sq, pKey);
    ef_knn_merge<<<(RN * MLANES) / 256, 256, 0, stream>>>(pKey, outIdxF);
    if (useT)
        ef_edge_kernelT<<<(BATCH * NPTS * KNN * 2) / 256, 256, 0, stream>>>(pcT, outIdxF, out);
    else
        ef_edge_kernel<<<(BATCH * NPTS * KNN) / 256, 256, 0, stream>>>(pc, outIdxF, out);
}